// Round 7
// baseline (224.330 us; speedup 1.0000x reference)
//
#include <hip/hip_runtime.h>
#include <stdint.h>

typedef __bf16 bf16;
typedef __bf16 bf16x4 __attribute__((ext_vector_type(4)));
typedef __bf16 bf16x8 __attribute__((ext_vector_type(8)));
typedef float f32x4 __attribute__((ext_vector_type(4)));
typedef short short4_t __attribute__((ext_vector_type(4)));

#define MFMA16(a, b, c) __builtin_amdgcn_mfma_f32_16x16x32_bf16((a), (b), (c), 0, 0, 0)

__device__ __forceinline__ f32x4 mfma1k(bf16x4 a, bf16x4 b, f32x4 c) {
    return __builtin_amdgcn_mfma_f32_16x16x16bf16_1k(
        __builtin_bit_cast(short4_t, a), __builtin_bit_cast(short4_t, b), c, 0, 0, 0);
}

#define EMBED 1024
#define SEQ   2048
#define MROWS 4096
#define ATTN_SCALE 0.125f

__device__ __forceinline__ void gl2lds16(const bf16* g, bf16* l) {
    __builtin_amdgcn_global_load_lds(
        (const __attribute__((address_space(1))) void*)g,
        (__attribute__((address_space(3))) void*)l,
        16, 0, 0);
}

// ---------------------------------------------------------------------------
// fused fp32 -> bf16 cast of x + 4 weight matrices (contiguous dst region)
// ---------------------------------------------------------------------------
__global__ __launch_bounds__(256) void cast_all_kernel(
    const float* __restrict__ x,  const float* __restrict__ Wq,
    const float* __restrict__ Wk, const float* __restrict__ Wv,
    const float* __restrict__ Wo, bf16* __restrict__ dst) {
    const int blk = blockIdx.x;
    const float* src;
    size_t so, dofs;
    if (blk < 2048) {
        src = x; so = (size_t)blk * 2048; dofs = so;
    } else {
        const int w = (blk - 2048) >> 9;
        so  = (size_t)((blk - 2048) & 511) * 2048;
        src = (w == 0) ? Wq : (w == 1) ? Wk : (w == 2) ? Wv : Wo;
        dofs = (size_t)(4 + w) * 1024 * 1024 + so;
    }
    const size_t i = (size_t)threadIdx.x * 8;
    float4 a = *(const float4*)(src + so + i);
    float4 b = *(const float4*)(src + so + i + 4);
    bf16x8 o;
    o[0] = (bf16)a.x; o[1] = (bf16)a.y; o[2] = (bf16)a.z; o[3] = (bf16)a.w;
    o[4] = (bf16)b.x; o[5] = (bf16)b.y; o[6] = (bf16)b.z; o[7] = (bf16)b.w;
    *(bf16x8*)(dst + dofs + i) = o;
}

// ---------------------------------------------------------------------------
// GEMM 128x128 tile, BK=64, 4 waves 2x2, fp32 accum, XOR-swizzled LDS.
// MODE 0: C[m][n] = x@W^T + b (bf16)
// MODE 1: same, scaled by ATTN_SCALE (for Q)
// MODE 2: swapped-operand MFMA -> output transposed: VT[(b*1024+n)][tok]
// ---------------------------------------------------------------------------
template <int MODE>
__device__ __forceinline__ void gemm_tile(const bf16* __restrict__ A,
                                          const bf16* __restrict__ W,
                                          const float* __restrict__ bias,
                                          bf16* __restrict__ C,
                                          int m0, int n0) {
    __shared__ bf16 As[128 * 64];
    __shared__ bf16 Bs[128 * 64];

    const int lane = threadIdx.x & 63;
    const int wv   = threadIdx.x >> 6;
    const int wm   = (wv >> 1) * 64;
    const int wn   = (wv & 1) * 64;
    const int fr   = lane & 15;
    const int quad = lane >> 4;
    const int srow = wv * 8 + (lane >> 3);
    const int swz  = (((lane & 7) ^ ((lane >> 3) & 7))) * 8;

    f32x4 acc[4][4];
#pragma unroll
    for (int mt = 0; mt < 4; ++mt)
#pragma unroll
        for (int nt = 0; nt < 4; ++nt)
            acc[mt][nt] = (f32x4){0.f, 0.f, 0.f, 0.f};

    for (int k0 = 0; k0 < 1024; k0 += 64) {
#pragma unroll
        for (int i = 0; i < 4; ++i) {
            gl2lds16(A + (size_t)(m0 + i * 32 + srow) * 1024 + k0 + swz,
                     &As[(i * 32 + wv * 8) * 64]);
            gl2lds16(W + (size_t)(n0 + i * 32 + srow) * 1024 + k0 + swz,
                     &Bs[(i * 32 + wv * 8) * 64]);
        }
        __syncthreads();
#pragma unroll
        for (int ks = 0; ks < 2; ++ks) {
            const int fcol = ((ks * 4 + quad) ^ (fr & 7)) * 8;
            bf16x8 af[4], bfr[4];
#pragma unroll
            for (int t = 0; t < 4; ++t) {
                af[t]  = *(const bf16x8*)&As[(wm + t * 16 + fr) * 64 + fcol];
                bfr[t] = *(const bf16x8*)&Bs[(wn + t * 16 + fr) * 64 + fcol];
            }
#pragma unroll
            for (int mt = 0; mt < 4; ++mt)
#pragma unroll
                for (int nt = 0; nt < 4; ++nt) {
                    if (MODE == 2)   // D[w-row][token]
                        acc[mt][nt] = MFMA16(bfr[mt], af[nt], acc[mt][nt]);
                    else             // D[token][w-row]
                        acc[mt][nt] = MFMA16(af[mt], bfr[nt], acc[mt][nt]);
                }
        }
        __syncthreads();
    }

    if (MODE == 2) {
        // rows n = n0+wn+mt*16+quad*4+r (d), cols tok = m0+wm+nt*16+fr
        const int bb    = m0 >> 11;
        const int tbase = (m0 & 2047) + wm;
        float4 b4[4];
#pragma unroll
        for (int mt = 0; mt < 4; ++mt)
            b4[mt] = *(const float4*)&bias[n0 + wn + mt * 16 + quad * 4];
#pragma unroll
        for (int mt = 0; mt < 4; ++mt)
#pragma unroll
            for (int nt = 0; nt < 4; ++nt)
#pragma unroll
                for (int r = 0; r < 4; ++r) {
                    const int n   = n0 + wn + mt * 16 + quad * 4 + r;
                    const int tok = tbase + nt * 16 + fr;
                    const float bvr = (r == 0) ? b4[mt].x : (r == 1) ? b4[mt].y
                                    : (r == 2) ? b4[mt].z : b4[mt].w;
                    C[((size_t)(bb * 1024 + n)) * 2048 + tok] =
                        (bf16)(acc[mt][nt][r] + bvr);
                }
    } else {
        float bv[4];
#pragma unroll
        for (int nt = 0; nt < 4; ++nt)
            bv[nt] = bias[n0 + wn + nt * 16 + fr];
        const int row4 = quad * 4;
#pragma unroll
        for (int mt = 0; mt < 4; ++mt)
#pragma unroll
            for (int nt = 0; nt < 4; ++nt)
#pragma unroll
                for (int r = 0; r < 4; ++r) {
                    int m = m0 + wm + mt * 16 + row4 + r;
                    int n = n0 + wn + nt * 16 + fr;
                    float v = acc[mt][nt][r] + bv[nt];
                    if (MODE == 1) v *= ATTN_SCALE;
                    C[(size_t)m * 1024 + n] = (bf16)v;
                }
    }
}

__global__ __launch_bounds__(256) void qkv_kernel(
    const bf16* __restrict__ x,
    const bf16* __restrict__ Wq, const float* __restrict__ bq,
    const bf16* __restrict__ Wk, const float* __restrict__ bk,
    const bf16* __restrict__ Wv, const float* __restrict__ bv,
    bf16* __restrict__ Q, bf16* __restrict__ K, bf16* __restrict__ VT) {
    const int m0    = blockIdx.x * 128;
    const int which = blockIdx.y >> 3;
    const int n0    = (blockIdx.y & 7) * 128;
    if (which == 0)      gemm_tile<1>(x, Wq, bq, Q,  m0, n0);
    else if (which == 1) gemm_tile<0>(x, Wk, bk, K,  m0, n0);
    else                 gemm_tile<2>(x, Wv, bv, VT, m0, n0);
}

// ---------------------------------------------------------------------------
// O-proj GEMM, 128x64 tile, BK=64, 4 waves 2x2, fp32 out.
// ---------------------------------------------------------------------------
__global__ __launch_bounds__(256) void oproj_kernel(
    const bf16* __restrict__ A, const bf16* __restrict__ W,
    const float* __restrict__ bias, float* __restrict__ C) {
    const int m0 = blockIdx.x * 128;
    const int n0 = blockIdx.y * 64;

    __shared__ bf16 As[128 * 64];
    __shared__ bf16 Bs[64 * 64];

    const int lane = threadIdx.x & 63;
    const int wv   = threadIdx.x >> 6;
    const int wm   = (wv >> 1) * 64;
    const int wn   = (wv & 1) * 32;
    const int fr   = lane & 15;
    const int quad = lane >> 4;
    const int srow = wv * 8 + (lane >> 3);
    const int swz  = (((lane & 7) ^ ((lane >> 3) & 7))) * 8;

    f32x4 acc[4][2];
#pragma unroll
    for (int mt = 0; mt < 4; ++mt)
#pragma unroll
        for (int nt = 0; nt < 2; ++nt)
            acc[mt][nt] = (f32x4){0.f, 0.f, 0.f, 0.f};

    for (int k0 = 0; k0 < 1024; k0 += 64) {
#pragma unroll
        for (int i = 0; i < 4; ++i)
            gl2lds16(A + (size_t)(m0 + i * 32 + srow) * 1024 + k0 + swz,
                     &As[(i * 32 + wv * 8) * 64]);
#pragma unroll
        for (int i = 0; i < 2; ++i)
            gl2lds16(W + (size_t)(n0 + i * 32 + srow) * 1024 + k0 + swz,
                     &Bs[(i * 32 + wv * 8) * 64]);
        __syncthreads();
#pragma unroll
        for (int ks = 0; ks < 2; ++ks) {
            const int fcol = ((ks * 4 + quad) ^ (fr & 7)) * 8;
            bf16x8 af[4], bfr[2];
#pragma unroll
            for (int t = 0; t < 4; ++t)
                af[t] = *(const bf16x8*)&As[(wm + t * 16 + fr) * 64 + fcol];
#pragma unroll
            for (int t = 0; t < 2; ++t)
                bfr[t] = *(const bf16x8*)&Bs[(wn + t * 16 + fr) * 64 + fcol];
#pragma unroll
            for (int mt = 0; mt < 4; ++mt)
#pragma unroll
                for (int nt = 0; nt < 2; ++nt)
                    acc[mt][nt] = MFMA16(af[mt], bfr[nt], acc[mt][nt]);
        }
        __syncthreads();
    }

    float bv[2];
#pragma unroll
    for (int nt = 0; nt < 2; ++nt)
        bv[nt] = bias[n0 + wn + nt * 16 + fr];
    const int row4 = quad * 4;
#pragma unroll
    for (int mt = 0; mt < 4; ++mt)
#pragma unroll
        for (int nt = 0; nt < 2; ++nt)
#pragma unroll
            for (int r = 0; r < 4; ++r) {
                int m = m0 + wm + mt * 16 + row4 + r;
                int n = n0 + wn + nt * 16 + fr;
                C[(size_t)m * 1024 + n] = acc[mt][nt][r] + bv[nt];
            }
}

// ---------------------------------------------------------------------------
// Flash attention v5: q-tile 128 (32 q/wave), Q pre-scaled, denominator via
// ones-row MFMA, zero-C S-init, KV loop unrolled x2 (compile-time buffer),
// K and V^T staged via swizzled global_load_lds, 1 barrier/iter.
// ---------------------------------------------------------------------------
__global__ __launch_bounds__(256) void attn_kernel(
    const bf16* __restrict__ Q, const bf16* __restrict__ K,
    const bf16* __restrict__ VT, bf16* __restrict__ O) {
    const int lane = threadIdx.x & 63;
    const int wv   = threadIdx.x >> 6;
    const int quad = lane >> 4;
    const int f    = lane & 15;
    const int q0   = blockIdx.x * 128;
    const int b    = blockIdx.y >> 4;
    const int h    = blockIdx.y & 15;

    const bf16* Qp = Q + ((size_t)b * SEQ) * 1024 + (size_t)h * 64;
    const bf16* Kp = K + ((size_t)b * SEQ) * 1024 + (size_t)h * 64;
    const bf16* Vp = VT + ((size_t)(b * 1024 + h * 64)) * 2048;   // [d][tok]
    bf16*       Op = O + ((size_t)b * SEQ) * 1024 + (size_t)h * 64;

    __shared__ bf16 Ks[2][64 * 64];    // [kv][d], swizzled 16B groups
    __shared__ bf16 VTs[2][64 * 64];   // [d][kv], swizzled 16B groups

    // Q fragments: wave handles 32 q-rows (2 groups of 16); pre-scaled in qkv.
    bf16x8 qf[2][2];
#pragma unroll
    for (int qg = 0; qg < 2; ++qg) {
        const bf16* qrow = Qp + (size_t)(q0 + wv * 32 + qg * 16 + f) * 1024;
        qf[qg][0] = *(const bf16x8*)(qrow + quad * 8);
        qf[qg][1] = *(const bf16x8*)(qrow + 32 + quad * 8);
    }

    const int srow = wv * 8 + (lane >> 3);
    const int swz  = (((lane & 7) ^ ((lane >> 3) & 7))) * 8;
    auto stageK = [&](int kv0, int buf) {
#pragma unroll
        for (int i = 0; i < 2; ++i)
            gl2lds16(Kp + (size_t)(kv0 + i * 32 + srow) * 1024 + swz,
                     &Ks[buf][(i * 32 + wv * 8) * 64]);
    };
    auto stageVT = [&](int kv0, int buf) {
#pragma unroll
        for (int i = 0; i < 2; ++i)
            gl2lds16(Vp + (size_t)(i * 32 + srow) * 2048 + kv0 + swz,
                     &VTs[buf][(i * 32 + wv * 8) * 64]);
    };

    stageK(0, 0);
    stageVT(0, 0);

    f32x4 oacc[2][4];
#pragma unroll
    for (int qg = 0; qg < 2; ++qg)
#pragma unroll
        for (int t = 0; t < 4; ++t)
            oacc[qg][t] = (f32x4){0.f, 0.f, 0.f, 0.f};
    f32x4 lacc[2];
    lacc[0] = (f32x4){0.f, 0.f, 0.f, 0.f};
    lacc[1] = (f32x4){0.f, 0.f, 0.f, 0.f};
    const bf16x4 onesb = {(bf16)1.f, (bf16)1.f, (bf16)1.f, (bf16)1.f};
    const f32x4  zero4 = (f32x4){0.f, 0.f, 0.f, 0.f};

    const int fcol0 = (quad ^ (f & 7)) * 8;
    const int fcol1 = ((4 + quad) ^ (f & 7)) * 8;

    __syncthreads();

    auto step = [&](int cur, int nextit) {
        if (nextit < SEQ / 64) {          // async prefetch before compute
            stageK(nextit * 64, cur ^ 1);
            stageVT(nextit * 64, cur ^ 1);
        }

        // ---- S^T = K Q^T ----
        bf16x8 kf0[4], kf1[4];
#pragma unroll
        for (int t = 0; t < 4; ++t) {
            kf0[t] = *(const bf16x8*)&Ks[cur][(t * 16 + f) * 64 + fcol0];
            kf1[t] = *(const bf16x8*)&Ks[cur][(t * 16 + f) * 64 + fcol1];
        }
        f32x4 s[2][4];
#pragma unroll
        for (int qg = 0; qg < 2; ++qg)
#pragma unroll
            for (int t = 0; t < 4; ++t) {
                s[qg][t] = MFMA16(kf0[t], qf[qg][0], zero4);
                s[qg][t] = MFMA16(kf1[t], qf[qg][1], s[qg][t]);
            }

        // ---- P^T = exp(S^T); denominator via ones-row MFMA ----
        bf16x4 pb[2][4];
#pragma unroll
        for (int qg = 0; qg < 2; ++qg)
#pragma unroll
            for (int t = 0; t < 4; ++t) {
#pragma unroll
                for (int r = 0; r < 4; ++r)
                    pb[qg][t][r] = (bf16)__expf(s[qg][t][r]);
                lacc[qg] = mfma1k(onesb, pb[qg][t], lacc[qg]);
            }

        // ---- O^T += V^T P^T ----
#pragma unroll
        for (int dt = 0; dt < 4; ++dt) {
#pragma unroll
            for (int kt = 0; kt < 4; ++kt) {
                const int pc = ((kt * 2 + (quad >> 1)) ^ (f & 7)) * 8 + (quad & 1) * 4;
                bf16x4 vf = *(const bf16x4*)&VTs[cur][(dt * 16 + f) * 64 + pc];
#pragma unroll
                for (int qg = 0; qg < 2; ++qg)
                    oacc[qg][dt] = mfma1k(vf, pb[qg][kt], oacc[qg][dt]);
            }
        }
        __syncthreads();
    };

    for (int it = 0; it < SEQ / 64; it += 2) {
        step(0, it + 1);
        step(1, it + 2);
    }

    // ---- normalize + store (lane holds q-row f; lacc col f = denominator) ----
#pragma unroll
    for (int qg = 0; qg < 2; ++qg) {
        const float inv = 1.0f / lacc[qg][0];
        bf16* orow = Op + (size_t)(q0 + wv * 32 + qg * 16 + f) * 1024;
#pragma unroll
        for (int dt = 0; dt < 4; ++dt) {
            bf16x4 ov;
#pragma unroll
            for (int r = 0; r < 4; ++r)
                ov[r] = (bf16)(oacc[qg][dt][r] * inv);
            *(bf16x4*)(orow + dt * 16 + quad * 4) = ov;
        }
    }
}

extern "C" void kernel_launch(void* const* d_in, const int* in_sizes, int n_in,
                              void* d_out, int out_size, void* d_ws, size_t ws_size,
                              hipStream_t stream) {
    const float* x  = (const float*)d_in[0];
    const float* Wq = (const float*)d_in[1];
    const float* bq = (const float*)d_in[2];
    const float* Wk = (const float*)d_in[3];
    const float* bk = (const float*)d_in[4];
    const float* Wv = (const float*)d_in[5];
    const float* bv = (const float*)d_in[6];
    const float* Wo = (const float*)d_in[7];
    const float* bo = (const float*)d_in[8];
    float* out = (float*)d_out;

    bf16* xb  = (bf16*)d_ws;
    bf16* Wqb = xb  + (size_t)MROWS * 1024;
    bf16* Wkb = Wqb + (size_t)1024 * 1024;
    bf16* Wvb = Wkb + (size_t)1024 * 1024;
    bf16* Wob = Wvb + (size_t)1024 * 1024;
    bf16* Q   = Wob + (size_t)1024 * 1024;
    bf16* K   = Q + (size_t)MROWS * 1024;
    bf16* VT  = K + (size_t)MROWS * 1024;   // [B*1024 rows][2048 tokens]
    bf16* O   = VT + (size_t)MROWS * 1024;

    cast_all_kernel<<<4096, 256, 0, stream>>>(x, Wq, Wk, Wv, Wo, xb);

    qkv_kernel<<<dim3(32, 24), 256, 0, stream>>>(xb, Wqb, bq, Wkb, bk, Wvb, bv, Q, K, VT);
    attn_kernel<<<dim3(16, 32), 256, 0, stream>>>(Q, K, VT, O);
    oproj_kernel<<<dim3(32, 16), 256, 0, stream>>>(O, Wob, bo, out);
}

// Round 8
// 207.474 us; speedup vs baseline: 1.0812x; 1.0812x over previous
//
#include <hip/hip_runtime.h>
#include <stdint.h>

typedef __bf16 bf16;
typedef __bf16 bf16x4 __attribute__((ext_vector_type(4)));
typedef __bf16 bf16x8 __attribute__((ext_vector_type(8)));
typedef float f32x4 __attribute__((ext_vector_type(4)));
typedef short short4_t __attribute__((ext_vector_type(4)));

#define MFMA16(a, b, c) __builtin_amdgcn_mfma_f32_16x16x32_bf16((a), (b), (c), 0, 0, 0)

__device__ __forceinline__ f32x4 mfma1k(bf16x4 a, bf16x4 b, f32x4 c) {
    return __builtin_amdgcn_mfma_f32_16x16x16bf16_1k(
        __builtin_bit_cast(short4_t, a), __builtin_bit_cast(short4_t, b), c, 0, 0, 0);
}

#define EMBED 1024
#define SEQ   2048
#define MROWS 4096
#define ATTN_SCALE 0.125f

__device__ __forceinline__ void gl2lds16(const bf16* g, bf16* l) {
    __builtin_amdgcn_global_load_lds(
        (const __attribute__((address_space(1))) void*)g,
        (__attribute__((address_space(3))) void*)l,
        16, 0, 0);
}

// ---------------------------------------------------------------------------
// fused fp32 -> bf16 cast of x + 4 weight matrices (contiguous dst region)
// ---------------------------------------------------------------------------
__global__ __launch_bounds__(256) void cast_all_kernel(
    const float* __restrict__ x,  const float* __restrict__ Wq,
    const float* __restrict__ Wk, const float* __restrict__ Wv,
    const float* __restrict__ Wo, bf16* __restrict__ dst) {
    const int blk = blockIdx.x;
    const float* src;
    size_t so, dofs;
    if (blk < 2048) {
        src = x; so = (size_t)blk * 2048; dofs = so;
    } else {
        const int w = (blk - 2048) >> 9;
        so  = (size_t)((blk - 2048) & 511) * 2048;
        src = (w == 0) ? Wq : (w == 1) ? Wk : (w == 2) ? Wv : Wo;
        dofs = (size_t)(4 + w) * 1024 * 1024 + so;
    }
    const size_t i = (size_t)threadIdx.x * 8;
    float4 a = *(const float4*)(src + so + i);
    float4 b = *(const float4*)(src + so + i + 4);
    bf16x8 o;
    o[0] = (bf16)a.x; o[1] = (bf16)a.y; o[2] = (bf16)a.z; o[3] = (bf16)a.w;
    o[4] = (bf16)b.x; o[5] = (bf16)b.y; o[6] = (bf16)b.z; o[7] = (bf16)b.w;
    *(bf16x8*)(dst + dofs + i) = o;
}

// ---------------------------------------------------------------------------
// Q/K GEMM 128x128 tile, BK=64, 4 waves 2x2, XOR-swizzled LDS.
// SCALE: multiply result by ATTN_SCALE (Q only).
// ---------------------------------------------------------------------------
template <bool SCALE>
__device__ __forceinline__ void gemm_tile(const bf16* __restrict__ A,
                                          const bf16* __restrict__ W,
                                          const float* __restrict__ bias,
                                          bf16* __restrict__ C,
                                          int m0, int n0) {
    __shared__ bf16 As[128 * 64];
    __shared__ bf16 Bs[128 * 64];

    const int lane = threadIdx.x & 63;
    const int wv   = threadIdx.x >> 6;
    const int wm   = (wv >> 1) * 64;
    const int wn   = (wv & 1) * 64;
    const int fr   = lane & 15;
    const int quad = lane >> 4;
    const int srow = wv * 8 + (lane >> 3);
    const int swz  = (((lane & 7) ^ ((lane >> 3) & 7))) * 8;

    f32x4 acc[4][4];
#pragma unroll
    for (int mt = 0; mt < 4; ++mt)
#pragma unroll
        for (int nt = 0; nt < 4; ++nt)
            acc[mt][nt] = (f32x4){0.f, 0.f, 0.f, 0.f};

    for (int k0 = 0; k0 < 1024; k0 += 64) {
#pragma unroll
        for (int i = 0; i < 4; ++i) {
            gl2lds16(A + (size_t)(m0 + i * 32 + srow) * 1024 + k0 + swz,
                     &As[(i * 32 + wv * 8) * 64]);
            gl2lds16(W + (size_t)(n0 + i * 32 + srow) * 1024 + k0 + swz,
                     &Bs[(i * 32 + wv * 8) * 64]);
        }
        __syncthreads();
#pragma unroll
        for (int ks = 0; ks < 2; ++ks) {
            const int fcol = ((ks * 4 + quad) ^ (fr & 7)) * 8;
            bf16x8 af[4], bfr[4];
#pragma unroll
            for (int t = 0; t < 4; ++t) {
                af[t]  = *(const bf16x8*)&As[(wm + t * 16 + fr) * 64 + fcol];
                bfr[t] = *(const bf16x8*)&Bs[(wn + t * 16 + fr) * 64 + fcol];
            }
#pragma unroll
            for (int mt = 0; mt < 4; ++mt)
#pragma unroll
                for (int nt = 0; nt < 4; ++nt)
                    acc[mt][nt] = MFMA16(af[mt], bfr[nt], acc[mt][nt]);
        }
        __syncthreads();
    }

    float bv[4];
#pragma unroll
    for (int nt = 0; nt < 4; ++nt)
        bv[nt] = bias[n0 + wn + nt * 16 + fr];
    const int row4 = quad * 4;
#pragma unroll
    for (int mt = 0; mt < 4; ++mt)
#pragma unroll
        for (int nt = 0; nt < 4; ++nt)
#pragma unroll
            for (int r = 0; r < 4; ++r) {
                int m = m0 + wm + mt * 16 + row4 + r;
                int n = n0 + wn + nt * 16 + fr;
                float v = acc[mt][nt][r] + bv[nt];
                if (SCALE) v *= ATTN_SCALE;
                C[(size_t)m * 1024 + n] = (bf16)v;
            }
}

__global__ __launch_bounds__(256) void qk_kernel(
    const bf16* __restrict__ x,
    const bf16* __restrict__ Wq, const float* __restrict__ bq,
    const bf16* __restrict__ Wk, const float* __restrict__ bk,
    bf16* __restrict__ Q, bf16* __restrict__ K) {
    const int m0 = blockIdx.x * 128;
    const int n0 = (blockIdx.y & 7) * 128;
    if (blockIdx.y < 8) gemm_tile<true>(x, Wq, bq, Q, m0, n0);
    else                gemm_tile<false>(x, Wk, bk, K, m0, n0);
}

// ---------------------------------------------------------------------------
// V^T GEMM: VT[(b*1024 + n)][tok] = sum_k Wv[n][k]*x[tok][k] + bv[n]
// Swapped-operand MFMA (D = W x^T) + LDS round-trip transpose epilogue
// -> fully-coalesced bf16x8 global stores.
// ---------------------------------------------------------------------------
__global__ __launch_bounds__(256) void v_kernel(
    const bf16* __restrict__ x, const bf16* __restrict__ Wv,
    const float* __restrict__ bias, bf16* __restrict__ VT) {
    const int m0 = blockIdx.x * 128;   // token tile
    const int n0 = blockIdx.y * 128;   // d rows (Wv rows)

    __shared__ __align__(16) bf16 smem[128 * 136];   // 34.8 KB, overlaid
    bf16* As = smem;              // x tile 128x64 (swizzled)
    bf16* Bs = smem + 128 * 64;   // W tile 128x64 (swizzled)

    const int lane = threadIdx.x & 63;
    const int wv   = threadIdx.x >> 6;
    const int wmW  = (wv >> 1) * 64;   // W-row half
    const int wnT  = (wv & 1) * 64;    // token half
    const int f    = lane & 15;
    const int quad = lane >> 4;
    const int srow = wv * 8 + (lane >> 3);
    const int swz  = (((lane & 7) ^ ((lane >> 3) & 7))) * 8;

    f32x4 acc[4][4];   // [mt: W rows][nt: tokens]
#pragma unroll
    for (int mt = 0; mt < 4; ++mt)
#pragma unroll
        for (int nt = 0; nt < 4; ++nt)
            acc[mt][nt] = (f32x4){0.f, 0.f, 0.f, 0.f};

    for (int k0 = 0; k0 < 1024; k0 += 64) {
#pragma unroll
        for (int i = 0; i < 4; ++i) {
            gl2lds16(x  + (size_t)(m0 + i * 32 + srow) * 1024 + k0 + swz,
                     &As[(i * 32 + wv * 8) * 64]);
            gl2lds16(Wv + (size_t)(n0 + i * 32 + srow) * 1024 + k0 + swz,
                     &Bs[(i * 32 + wv * 8) * 64]);
        }
        __syncthreads();
#pragma unroll
        for (int ks = 0; ks < 2; ++ks) {
            const int fcol = ((ks * 4 + quad) ^ (f & 7)) * 8;
            bf16x8 wf[4], xf[4];
#pragma unroll
            for (int t = 0; t < 4; ++t) {
                wf[t] = *(const bf16x8*)&Bs[(wmW + t * 16 + f) * 64 + fcol];
                xf[t] = *(const bf16x8*)&As[(wnT + t * 16 + f) * 64 + fcol];
            }
#pragma unroll
            for (int mt = 0; mt < 4; ++mt)
#pragma unroll
                for (int nt = 0; nt < 4; ++nt)
                    acc[mt][nt] = MFMA16(wf[mt], xf[nt], acc[mt][nt]);
        }
        __syncthreads();
    }

    // bias along d (broadcast across f lanes)
    float4 b4[4];
#pragma unroll
    for (int mt = 0; mt < 4; ++mt)
        b4[mt] = *(const float4*)&bias[n0 + wmW + mt * 16 + quad * 4];

    // write D[n_local][tok_local] into LDS tile, stride 136
#pragma unroll
    for (int mt = 0; mt < 4; ++mt)
#pragma unroll
        for (int nt = 0; nt < 4; ++nt) {
            const int tok = wnT + nt * 16 + f;
#pragma unroll
            for (int r = 0; r < 4; ++r) {
                const float bvr = (r == 0) ? b4[mt].x : (r == 1) ? b4[mt].y
                                : (r == 2) ? b4[mt].z : b4[mt].w;
                smem[(wmW + mt * 16 + quad * 4 + r) * 136 + tok] =
                    (bf16)(acc[mt][nt][r] + bvr);
            }
        }
    __syncthreads();

    // coalesced store: 8 passes, each thread stores bf16x8 along tok
    const int n_r  = threadIdx.x >> 4;            // 0..15
    const int t8   = (threadIdx.x & 15) * 8;      // 0..120
    const int bb   = m0 >> 11;
    const int tokg = (m0 & 2047) + t8;
#pragma unroll
    for (int p = 0; p < 8; ++p) {
        const int n_loc = p * 16 + n_r;
        bf16x8 v = *(const bf16x8*)&smem[n_loc * 136 + t8];
        *(bf16x8*)&VT[((size_t)(bb * 1024 + n0 + n_loc)) * 2048 + tokg] = v;
    }
}

// ---------------------------------------------------------------------------
// O-proj GEMM, 128x64 tile, BK=64, 4 waves 2x2, fp32 out.
// ---------------------------------------------------------------------------
__global__ __launch_bounds__(256) void oproj_kernel(
    const bf16* __restrict__ A, const bf16* __restrict__ W,
    const float* __restrict__ bias, float* __restrict__ C) {
    const int m0 = blockIdx.x * 128;
    const int n0 = blockIdx.y * 64;

    __shared__ bf16 As[128 * 64];
    __shared__ bf16 Bs[64 * 64];

    const int lane = threadIdx.x & 63;
    const int wv   = threadIdx.x >> 6;
    const int wm   = (wv >> 1) * 64;
    const int wn   = (wv & 1) * 32;
    const int fr   = lane & 15;
    const int quad = lane >> 4;
    const int srow = wv * 8 + (lane >> 3);
    const int swz  = (((lane & 7) ^ ((lane >> 3) & 7))) * 8;

    f32x4 acc[4][2];
#pragma unroll
    for (int mt = 0; mt < 4; ++mt)
#pragma unroll
        for (int nt = 0; nt < 2; ++nt)
            acc[mt][nt] = (f32x4){0.f, 0.f, 0.f, 0.f};

    for (int k0 = 0; k0 < 1024; k0 += 64) {
#pragma unroll
        for (int i = 0; i < 4; ++i)
            gl2lds16(A + (size_t)(m0 + i * 32 + srow) * 1024 + k0 + swz,
                     &As[(i * 32 + wv * 8) * 64]);
#pragma unroll
        for (int i = 0; i < 2; ++i)
            gl2lds16(W + (size_t)(n0 + i * 32 + srow) * 1024 + k0 + swz,
                     &Bs[(i * 32 + wv * 8) * 64]);
        __syncthreads();
#pragma unroll
        for (int ks = 0; ks < 2; ++ks) {
            const int fcol = ((ks * 4 + quad) ^ (fr & 7)) * 8;
            bf16x8 af[4], bfr[2];
#pragma unroll
            for (int t = 0; t < 4; ++t)
                af[t] = *(const bf16x8*)&As[(wm + t * 16 + fr) * 64 + fcol];
#pragma unroll
            for (int t = 0; t < 2; ++t)
                bfr[t] = *(const bf16x8*)&Bs[(wn + t * 16 + fr) * 64 + fcol];
#pragma unroll
            for (int mt = 0; mt < 4; ++mt)
#pragma unroll
                for (int nt = 0; nt < 2; ++nt)
                    acc[mt][nt] = MFMA16(af[mt], bfr[nt], acc[mt][nt]);
        }
        __syncthreads();
    }

    float bv[2];
#pragma unroll
    for (int nt = 0; nt < 2; ++nt)
        bv[nt] = bias[n0 + wn + nt * 16 + fr];
    const int row4 = quad * 4;
#pragma unroll
    for (int mt = 0; mt < 4; ++mt)
#pragma unroll
        for (int nt = 0; nt < 2; ++nt)
#pragma unroll
            for (int r = 0; r < 4; ++r) {
                int m = m0 + wm + mt * 16 + row4 + r;
                int n = n0 + wn + nt * 16 + fr;
                C[(size_t)m * 1024 + n] = acc[mt][nt][r] + bv[nt];
            }
}

// ---------------------------------------------------------------------------
// Flash attention v6: 512 threads (8 waves), q-tile 128 (16 q/wave),
// S^T formulation, Q pre-scaled, denominator via ones-row MFMA,
// single gl2lds per K/V tile, double-buffered, 1 barrier/iter, unroll x2.
// ---------------------------------------------------------------------------
__global__ __launch_bounds__(512) void attn_kernel(
    const bf16* __restrict__ Q, const bf16* __restrict__ K,
    const bf16* __restrict__ VT, bf16* __restrict__ O) {
    const int tid  = threadIdx.x;
    const int lane = tid & 63;
    const int wv   = tid >> 6;       // 0..7
    const int quad = lane >> 4;
    const int f    = lane & 15;
    const int q0   = blockIdx.x * 128;
    const int b    = blockIdx.y >> 4;
    const int h    = blockIdx.y & 15;

    const bf16* Qp = Q + ((size_t)b * SEQ) * 1024 + (size_t)h * 64;
    const bf16* Kp = K + ((size_t)b * SEQ) * 1024 + (size_t)h * 64;
    const bf16* Vp = VT + ((size_t)(b * 1024 + h * 64)) * 2048;   // [d][tok]
    bf16*       Op = O + ((size_t)b * SEQ) * 1024 + (size_t)h * 64;

    __shared__ bf16 Ks[2][64 * 64];    // [kv][d], swizzled 16B groups
    __shared__ bf16 VTs[2][64 * 64];   // [d][kv], swizzled 16B groups

    // Q fragments: wave handles q rows q0 + wv*16 + f (pre-scaled in qk_kernel)
    bf16x8 qf[2];
    {
        const bf16* qrow = Qp + (size_t)(q0 + wv * 16 + f) * 1024;
        qf[0] = *(const bf16x8*)(qrow + quad * 8);
        qf[1] = *(const bf16x8*)(qrow + 32 + quad * 8);
    }

    const int srow = tid >> 3;                              // 0..63
    const int swz  = (((tid & 7) ^ ((tid >> 3) & 7))) * 8;
    auto stageK = [&](int kv0, int buf) {
        gl2lds16(Kp + (size_t)(kv0 + srow) * 1024 + swz, &Ks[buf][wv * 512]);
    };
    auto stageVT = [&](int kv0, int buf) {
        gl2lds16(Vp + (size_t)srow * 2048 + kv0 + swz, &VTs[buf][wv * 512]);
    };

    stageK(0, 0);
    stageVT(0, 0);

    f32x4 oacc[4];
#pragma unroll
    for (int t = 0; t < 4; ++t)
        oacc[t] = (f32x4){0.f, 0.f, 0.f, 0.f};
    f32x4 lacc = (f32x4){0.f, 0.f, 0.f, 0.f};
    const bf16x4 onesb = {(bf16)1.f, (bf16)1.f, (bf16)1.f, (bf16)1.f};
    const f32x4  zero4 = (f32x4){0.f, 0.f, 0.f, 0.f};

    const int fcol0 = (quad ^ (f & 7)) * 8;
    const int fcol1 = ((4 + quad) ^ (f & 7)) * 8;

    __syncthreads();

    auto step = [&](int cur, int nextit) {
        if (nextit < SEQ / 64) {          // async prefetch before compute
            stageK(nextit * 64, cur ^ 1);
            stageVT(nextit * 64, cur ^ 1);
        }

        // ---- S^T = K Q^T: 4 tiles of 16 kv x 16 q ----
        f32x4 s[4];
#pragma unroll
        for (int t = 0; t < 4; ++t) {
            bf16x8 k0 = *(const bf16x8*)&Ks[cur][(t * 16 + f) * 64 + fcol0];
            bf16x8 k1 = *(const bf16x8*)&Ks[cur][(t * 16 + f) * 64 + fcol1];
            s[t] = MFMA16(k0, qf[0], zero4);
            s[t] = MFMA16(k1, qf[1], s[t]);
        }

        // ---- P^T = exp(S^T); denominator via ones-row MFMA ----
        bf16x4 pb[4];
#pragma unroll
        for (int t = 0; t < 4; ++t) {
#pragma unroll
            for (int r = 0; r < 4; ++r)
                pb[t][r] = (bf16)__expf(s[t][r]);
            lacc = mfma1k(onesb, pb[t], lacc);
        }

        // ---- O^T += V^T P^T ----
#pragma unroll
        for (int dt = 0; dt < 4; ++dt) {
#pragma unroll
            for (int kt = 0; kt < 4; ++kt) {
                const int pc = ((kt * 2 + (quad >> 1)) ^ (f & 7)) * 8 + (quad & 1) * 4;
                bf16x4 vf = *(const bf16x4*)&VTs[cur][(dt * 16 + f) * 64 + pc];
                oacc[dt] = mfma1k(vf, pb[kt], oacc[dt]);
            }
        }
        __syncthreads();
    };

    for (int it = 0; it < SEQ / 64; it += 2) {
        step(0, it + 1);
        step(1, it + 2);
    }

    // ---- normalize + store (lacc col f = denominator for q-row f) ----
    const float inv = 1.0f / lacc[0];
    bf16* orow = Op + (size_t)(q0 + wv * 16 + f) * 1024;
#pragma unroll
    for (int dt = 0; dt < 4; ++dt) {
        bf16x4 ov;
#pragma unroll
        for (int r = 0; r < 4; ++r)
            ov[r] = (bf16)(oacc[dt][r] * inv);
        *(bf16x4*)(orow + dt * 16 + quad * 4) = ov;
    }
}

extern "C" void kernel_launch(void* const* d_in, const int* in_sizes, int n_in,
                              void* d_out, int out_size, void* d_ws, size_t ws_size,
                              hipStream_t stream) {
    const float* x  = (const float*)d_in[0];
    const float* Wq = (const float*)d_in[1];
    const float* bq = (const float*)d_in[2];
    const float* Wk = (const float*)d_in[3];
    const float* bk = (const float*)d_in[4];
    const float* Wv = (const float*)d_in[5];
    const float* bv = (const float*)d_in[6];
    const float* Wo = (const float*)d_in[7];
    const float* bo = (const float*)d_in[8];
    float* out = (float*)d_out;

    bf16* xb  = (bf16*)d_ws;
    bf16* Wqb = xb  + (size_t)MROWS * 1024;
    bf16* Wkb = Wqb + (size_t)1024 * 1024;
    bf16* Wvb = Wkb + (size_t)1024 * 1024;
    bf16* Wob = Wvb + (size_t)1024 * 1024;
    bf16* Q   = Wob + (size_t)1024 * 1024;
    bf16* K   = Q + (size_t)MROWS * 1024;
    bf16* VT  = K + (size_t)MROWS * 1024;   // [B*1024 rows][2048 tokens]
    bf16* O   = VT + (size_t)MROWS * 1024;

    cast_all_kernel<<<4096, 256, 0, stream>>>(x, Wq, Wk, Wv, Wo, xb);

    qk_kernel<<<dim3(32, 16), 256, 0, stream>>>(xb, Wqb, bq, Wkb, bk, Q, K);
    v_kernel<<<dim3(32, 8), 256, 0, stream>>>(xb, Wvb, bv, VT);
    attn_kernel<<<dim3(16, 32), 512, 0, stream>>>(Q, K, VT, O);
    oproj_kernel<<<dim3(32, 16), 256, 0, stream>>>(O, Wob, bo, out);
}